// Round 1
// baseline (467.445 us; speedup 1.0000x reference)
//
#include <hip/hip_runtime.h>
#include <stdint.h>
#include <stddef.h>

// ---------------------------------------------------------------------------
// WQLinear: out[M][N] = x[M][K] * W[N][K]^T + bias
//   M=4096, K=4096, N=11008; W = int4 AWQ dequant (group 128)
// Pass 1: dequant W -> bf16 ws, x -> bf16 ws.
// Pass 2: 256x256x64 8-wave MFMA GEMM, read-ahead 4-phase pipeline.
//   This round: 16x16x32 -> 32x32x16 MFMA (2382-2495 TF ceiling vs 2075-2176,
//   same LDS traffic / read count / swizzle / staging schedule).
//   A-frag: row=lane&31, k=(lane>>5)*8+j ; B-frag: col=lane&31, same k.
//   C/D: col=lane&31, row=(reg&3)+8*(reg>>2)+4*(lane>>5)  [m74/m101].
// ---------------------------------------------------------------------------

#define M_DIM 4096
#define N_DIM 11008
#define K_DIM 4096
#define NT    (K_DIM / 64)          // 64 K-tiles

typedef __bf16 bf16x8 __attribute__((ext_vector_type(8)));
typedef float f32x4 __attribute__((ext_vector_type(4)));
typedef float f32x16 __attribute__((ext_vector_type(16)));
typedef unsigned int u32x4 __attribute__((ext_vector_type(4)));
typedef unsigned short u16x8 __attribute__((ext_vector_type(8)));
typedef unsigned short u16x4 __attribute__((ext_vector_type(4)));

__device__ __forceinline__ unsigned short f2bf(float f) {
    unsigned int u = __float_as_uint(f);
    u += 0x7fffu + ((u >> 16) & 1u);   // round-to-nearest-even
    return (unsigned short)(u >> 16);
}

typedef const __attribute__((address_space(1))) void* as1_cptr;
typedef __attribute__((address_space(3))) void* as3_ptr;

__device__ __forceinline__ void gl_lds16(const void* g, void* l) {
    __builtin_amdgcn_global_load_lds((as1_cptr)g, (as3_ptr)l, 16, 0, 0);
}

#define MFMA16(A, B, C) __builtin_amdgcn_mfma_f32_16x16x32_bf16((A), (B), (C), 0, 0, 0)
#define MFMA32(A, B, C) __builtin_amdgcn_mfma_f32_32x32x16_bf16((A), (B), (C), 0, 0, 0)

// ---- pre-kernel 1: dequant W (int4 -> bf16 row-major [N][K]) ----
__global__ __launch_bounds__(256)
void dequant_w_kernel(const int* __restrict__ qw, const int* __restrict__ qz,
                      const float* __restrict__ sc, unsigned short* __restrict__ Wbf)
{
    int idx = blockIdx.x * 256 + threadIdx.x;
    int n = idx >> 9;          // K/8 = 512 packed per row
    int p = idx & 511;
    int g = p >> 4;            // group = (p*8)/128
    unsigned int zw = (unsigned int)qz[n * 4 + (g >> 3)];
    float z = (float)((zw >> ((g & 7) * 4)) & 15u);
    float s = sc[n * 32 + g];
    float nz = -z * s;
    unsigned int w = (unsigned int)qw[idx];
    u16x8 t;
#pragma unroll
    for (int j = 0; j < 8; ++j) {
        float q = (float)((w >> (4 * j)) & 15u);
        t[j] = f2bf(__builtin_fmaf(q, s, nz));
    }
    *(u16x8*)(Wbf + (size_t)idx * 8) = t;
}

// ---- pre-kernel 2: x fp32 -> bf16 row-major [M][K] ----
__global__ __launch_bounds__(256)
void conv_x_kernel(const float* __restrict__ x, unsigned short* __restrict__ Xbf)
{
    size_t i8 = ((size_t)blockIdx.x * 256 + threadIdx.x) * 8;
    f32x4 a = *(const f32x4*)(x + i8);
    f32x4 b = *(const f32x4*)(x + i8 + 4);
    u16x8 t;
#pragma unroll
    for (int j = 0; j < 4; ++j) t[j] = f2bf(a[j]);
#pragma unroll
    for (int j = 0; j < 4; ++j) t[4 + j] = f2bf(b[j]);
    *(u16x8*)(Xbf + i8) = t;
}

// ---- main GEMM: 256x256 tile, BK=64, 8 waves (2x4), read-ahead pipeline ----
// Quadrant order Q00,Q01,Q10,Q11. Phase i computes Q(i) with regs read in
// phase i-1 body, reads regs for phase i+1, and issues the half-tile staging
// for tile t+2 (region-legality + vmcnt(12) landing schedule unchanged from
// the verified 16x16 version: each read's data lands at the wait 1 phase
// before the read, 6 phases in flight).
//
// 32x32x16 fragment reads: desired 16B chunk index within a 128B row is
// (2*kk + (lane>>5)); stored chunk = desired ^ (row&7) = desired ^ (lane&7).
#define LDA32(BASE, MHc, fmc, kkc) \
    __builtin_bit_cast(bf16x8, *(const u32x4*)((BASE) + (MHc)*16384 + (fmc)*4096 + a_rd + (swz32 ^ ((kkc)*32))))
#define LDB32(BASE, NHc, kkc) \
    __builtin_bit_cast(bf16x8, *(const u32x4*)((BASE) + (NHc)*16384 + b_rd + (swz32 ^ ((kkc)*32))))

#define WAIT_BAR1()                                         \
    asm volatile("s_waitcnt vmcnt(12)" ::: "memory");       \
    __builtin_amdgcn_s_barrier();                           \
    asm volatile("" ::: "memory");                          \
    __builtin_amdgcn_s_setprio(1);

#define END_PHASE()                                         \
    __builtin_amdgcn_s_setprio(0);                          \
    asm volatile("s_waitcnt lgkmcnt(0)" ::: "memory");      \
    __builtin_amdgcn_sched_barrier(0);                      \
    __builtin_amdgcn_s_barrier();                           \
    asm volatile("" ::: "memory");

__global__ __launch_bounds__(512, 2)
void gemm256_kernel(const unsigned short* __restrict__ Xbf,
                    const unsigned short* __restrict__ Wbf,
                    const float* __restrict__ bias,
                    float* __restrict__ out)
{
    __shared__ u32x4 lds4[8192];            // 128 KiB
    char* ldsA = (char*)lds4;               // A: [2 buf][256 rows][128 B]
    char* ldsB = ldsA + 65536;              // B: [2 buf][256 rows][128 B]

    const int tid = threadIdx.x;
    const int lane = tid & 63, wid = tid >> 6;
    const int l32 = lane & 31, l2 = lane >> 5;
    const int wm = wid >> 2, wn = wid & 3;

    // XCD-aware bijective swizzle: 688 blocks = 8 XCD x 86; per XCD 2x43
    // rectangle walked column-major.
    const int bid = blockIdx.x;
    const int xcd = bid & 7, c = bid >> 3;
    const int tm = 2 * xcd + (c & 1), tn = c >> 1;
    const int m0 = tm * 256, n0 = tn * 256;

    const int swz32 = ((l2 ^ (lane & 7)) << 4);        // read-side XOR (bytes)
    const int a_rd = (wm * 64 + l32) * 128;
    const int b_rd = (wn * 32 + l32) * 128;
    // inverse-swizzled per-lane global offset (linear LDS dst, swizzled src)
    const size_t goff = (size_t)(lane >> 3) * 8192 + (size_t)(((lane & 7) ^ (lane >> 3)) << 4);

    const char* pAg = (const char*)Xbf + (size_t)m0 * 8192 + goff;
    const char* pBg = (const char*)Wbf + (size_t)n0 * 8192 + goff;
    const size_t rowA = (size_t)(wid * 8) * 8192;       // rows 0-63 (8/wave)
    const size_t rowB = (size_t)((wid + 8) * 8) * 8192; // rows 64-127
    const int ldst0 = wid * 1024, ldst1 = (wid + 8) * 1024;

    // acc[MH*2+fm][NH]: 4 M-frags of 32 x 2 N-frags of 32, f32x16 each
    f32x16 acc[4][2];
#pragma unroll
    for (int i = 0; i < 4; ++i)
#pragma unroll
        for (int j = 0; j < 2; ++j)
#pragma unroll
            for (int r = 0; r < 16; ++r) acc[i][j][r] = 0.f;

    float bvv[2];
#pragma unroll
    for (int q = 0; q < 2; ++q)
        bvv[q] = bias[n0 + q * 128 + wn * 32 + l32];

    bf16x8 a0[2][4], a1[2][4], b0[4], b1[4];

    // ---- prologue: stage tiles 0 and 1 (order A_s0,B_s0,B_s1,A_s1 each) ----
    gl_lds16(pAg + rowA, ldsA + ldst0);
    gl_lds16(pAg + rowB, ldsA + ldst1);
    gl_lds16(pBg + rowA, ldsB + ldst0);
    gl_lds16(pBg + rowB, ldsB + ldst1);
    gl_lds16(pBg + 1048576 + rowA, ldsB + 16384 + ldst0);
    gl_lds16(pBg + 1048576 + rowB, ldsB + 16384 + ldst1);
    gl_lds16(pAg + 1048576 + rowA, ldsA + 16384 + ldst0);
    gl_lds16(pAg + 1048576 + rowB, ldsA + 16384 + ldst1);
    gl_lds16(pAg + rowA + 128, ldsA + 32768 + ldst0);
    gl_lds16(pAg + rowB + 128, ldsA + 32768 + ldst1);
    gl_lds16(pBg + rowA + 128, ldsB + 32768 + ldst0);
    gl_lds16(pBg + rowB + 128, ldsB + 32768 + ldst1);
    gl_lds16(pBg + 1048576 + rowA + 128, ldsB + 49152 + ldst0);
    gl_lds16(pBg + 1048576 + rowB + 128, ldsB + 49152 + ldst1);
    gl_lds16(pAg + 1048576 + rowA + 128, ldsA + 49152 + ldst0);
    gl_lds16(pAg + 1048576 + rowB + 128, ldsA + 49152 + ldst1);
    asm volatile("s_waitcnt vmcnt(12)" ::: "memory");   // A_s0(0), B_s0(0) landed
    __builtin_amdgcn_s_barrier();
    asm volatile("" ::: "memory");
    // prologue reads: a0(0), b0(0) from buffer 0
#pragma unroll
    for (int fm = 0; fm < 2; ++fm)
#pragma unroll
        for (int kk = 0; kk < 4; ++kk)
            a0[fm][kk] = LDA32(ldsA, 0, fm, kk);
#pragma unroll
    for (int kk = 0; kk < 4; ++kk)
        b0[kk] = LDB32(ldsB, 0, kk);
    asm volatile("s_waitcnt lgkmcnt(0)" ::: "memory");
    __builtin_amdgcn_sched_barrier(0);
    __builtin_amdgcn_s_barrier();
    asm volatile("" ::: "memory");

#pragma unroll 2
    for (int t = 0; t < NT; ++t) {
        const int p = t & 1;
        char* Ap = ldsA + p * 32768;
        char* Bp = ldsB + p * 32768;
        char* An = ldsA + (p ^ 1) * 32768;
        char* Bn = ldsB + (p ^ 1) * 32768;
        const size_t k2 = (size_t)((t + 2 < NT ? t + 2 : NT - 1) * 128);

        // == phase 0: Q00 = a0*b0 ; read b1(t) ; issue A_s0(t+2) -> Ap ==
        gl_lds16(pAg + rowA + k2, Ap + ldst0);
        gl_lds16(pAg + rowB + k2, Ap + ldst1);
        WAIT_BAR1();
#pragma unroll
        for (int kk = 0; kk < 4; ++kk)
            b1[kk] = LDB32(Bp, 1, kk);
#pragma unroll
        for (int kk = 0; kk < 4; ++kk) {
            acc[0][0] = MFMA32(a0[0][kk], b0[kk], acc[0][0]);
            acc[1][0] = MFMA32(a0[1][kk], b0[kk], acc[1][0]);
        }
        END_PHASE();

        // == phase 1: Q01 = a0*b1 ; read a1(t) ; issue B_s0(t+2) -> Bp ==
        gl_lds16(pBg + rowA + k2, Bp + ldst0);
        gl_lds16(pBg + rowB + k2, Bp + ldst1);
        WAIT_BAR1();
#pragma unroll
        for (int fm = 0; fm < 2; ++fm)
#pragma unroll
            for (int kk = 0; kk < 4; ++kk)
                a1[fm][kk] = LDA32(Ap, 1, fm, kk);
#pragma unroll
        for (int kk = 0; kk < 4; ++kk) {
            acc[0][1] = MFMA32(a0[0][kk], b1[kk], acc[0][1]);
            acc[1][1] = MFMA32(a0[1][kk], b1[kk], acc[1][1]);
        }
        END_PHASE();

        // == phase 2: Q10 = a1*b0 ; read a0(t+1) kk=0,1 ; issue B_s1(t+2) -> Bp+16K ==
        gl_lds16(pBg + 1048576 + rowA + k2, Bp + 16384 + ldst0);
        gl_lds16(pBg + 1048576 + rowB + k2, Bp + 16384 + ldst1);
        WAIT_BAR1();
#pragma unroll
        for (int fm = 0; fm < 2; ++fm)
#pragma unroll
            for (int kk = 0; kk < 2; ++kk)
                a0[fm][kk] = LDA32(An, 0, fm, kk);
#pragma unroll
        for (int kk = 0; kk < 4; ++kk) {
            acc[2][0] = MFMA32(a1[0][kk], b0[kk], acc[2][0]);
            acc[3][0] = MFMA32(a1[1][kk], b0[kk], acc[3][0]);
        }
        END_PHASE();

        // == phase 3: Q11 = a1*b1 ; read a0(t+1) kk=2,3 + b0(t+1) ; issue A_s1(t+2) -> Ap+16K ==
        gl_lds16(pAg + 1048576 + rowA + k2, Ap + 16384 + ldst0);
        gl_lds16(pAg + 1048576 + rowB + k2, Ap + 16384 + ldst1);
        WAIT_BAR1();
#pragma unroll
        for (int fm = 0; fm < 2; ++fm)
#pragma unroll
            for (int kk = 2; kk < 4; ++kk)
                a0[fm][kk] = LDA32(An, 0, fm, kk);
#pragma unroll
        for (int kk = 0; kk < 4; ++kk)
            b0[kk] = LDB32(Bn, 0, kk);
#pragma unroll
        for (int kk = 0; kk < 4; ++kk) {
            acc[2][1] = MFMA32(a1[0][kk], b1[kk], acc[2][1]);
            acc[3][1] = MFMA32(a1[1][kk], b1[kk], acc[3][1]);
        }
        END_PHASE();
    }

    asm volatile("s_waitcnt vmcnt(0)" ::: "memory");   // drain dummy restage

    // epilogue: 32x32 C/D layout col=lane&31, row=(reg&3)+8*(reg>>2)+4*(lane>>5)
#pragma unroll
    for (int MH = 0; MH < 2; ++MH)
#pragma unroll
        for (int fm = 0; fm < 2; ++fm) {
            size_t rbase = (size_t)(m0 + MH * 128 + wm * 64 + fm * 32 + l2 * 4);
#pragma unroll
            for (int NH = 0; NH < 2; ++NH) {
                int col = n0 + NH * 128 + wn * 32 + l32;
                f32x16 v = acc[MH * 2 + fm][NH];
                float bb = bvv[NH];
#pragma unroll
                for (int r = 0; r < 16; ++r) {
                    size_t row = rbase + (size_t)((r & 3) + 8 * (r >> 2));
                    out[row * N_DIM + col] = v[r] + bb;
                }
            }
        }
}

// ---- fallback (no-ws): round-1 fused-dequant 128^2 kernel (verified) ----
__global__ __launch_bounds__(256, 2)
void gemm_fallback(const float* __restrict__ x,
                   const int* __restrict__ qweight,
                   const int* __restrict__ qzeros,
                   const float* __restrict__ scales,
                   const float* __restrict__ bias,
                   float* __restrict__ out)
{
    __shared__ u32x4 lds_raw[2048];
    char* ldsA = (char*)lds_raw;
    char* ldsB = ldsA + 16384;

    const int tid = threadIdx.x;
    const int n0 = blockIdx.x * 128;
    const int m0 = blockIdx.y * 128;
    const int wave = tid >> 6;
    const int lane = tid & 63;
    const int l16 = lane & 15;
    const int g4 = lane >> 4;
    const int wm = wave >> 1;
    const int wn = wave & 1;

    f32x4 acc[4][4];
#pragma unroll
    for (int i = 0; i < 4; ++i)
#pragma unroll
        for (int j = 0; j < 4; ++j) acc[i][j] = f32x4{0.f, 0.f, 0.f, 0.f};

    for (int kt = 0; kt < K_DIM / 64; ++kt) {
        __syncthreads();
#pragma unroll
        for (int i = 0; i < 4; ++i) {
            int cI = tid + i * 256;
            int row = cI >> 4, cc = cI & 15;
            f32x4 v = *(const f32x4*)(x + ((size_t)(m0 + row) * K_DIM + kt * 64 + cc * 4));
            u16x4 h;
#pragma unroll
            for (int j = 0; j < 4; ++j) h[j] = f2bf(v[j]);
            int b = row * 128 + cc * 8;
            *(u16x4*)(ldsA + (b ^ ((row & 7) << 4))) = h;
        }
        {
            int row = tid >> 1, half = tid & 1;
            int n = n0 + row;
            int g = kt >> 1;
            unsigned int zw = (unsigned int)qzeros[n * 4 + (g >> 3)];
            float z = (float)((zw >> ((g & 7) * 4)) & 15u);
            float s = scales[n * 32 + g];
            float nz = -z * s;
            u32x4 w4 = *(const u32x4*)(qweight + (size_t)n * 512 + kt * 8 + half * 4);
#pragma unroll
            for (int j4 = 0; j4 < 4; ++j4) {
                unsigned int w = w4[j4];
                u16x8 tt;
#pragma unroll
                for (int j = 0; j < 8; ++j) {
                    float q = (float)((w >> (4 * j)) & 15u);
                    tt[j] = f2bf(__builtin_fmaf(q, s, nz));
                }
                int b = row * 128 + half * 64 + j4 * 16;
                *(u16x8*)(ldsB + (b ^ ((row & 7) << 4))) = tt;
            }
        }
        __syncthreads();

#pragma unroll
        for (int kk = 0; kk < 2; ++kk) {
            bf16x8 af[4], bfm[4];
#pragma unroll
            for (int fm = 0; fm < 4; ++fm) {
                int arow = wm * 64 + fm * 16 + l16;
                int ab = arow * 128 + kk * 64 + g4 * 16;
                af[fm] = __builtin_bit_cast(bf16x8, *(const u32x4*)(ldsA + (ab ^ ((arow & 7) << 4))));
            }
#pragma unroll
            for (int fn = 0; fn < 4; ++fn) {
                int brow = wn * 64 + fn * 16 + l16;
                int bb = brow * 128 + kk * 64 + g4 * 16;
                bfm[fn] = __builtin_bit_cast(bf16x8, *(const u32x4*)(ldsB + (bb ^ ((brow & 7) << 4))));
            }
#pragma unroll
            for (int fm = 0; fm < 4; ++fm)
#pragma unroll
                for (int fn = 0; fn < 4; ++fn)
                    acc[fm][fn] = MFMA16(af[fm], bfm[fn], acc[fm][fn]);
        }
    }

#pragma unroll
    for (int fm = 0; fm < 4; ++fm) {
        int row0 = m0 + wm * 64 + fm * 16 + g4 * 4;
#pragma unroll
        for (int fn = 0; fn < 4; ++fn) {
            int col = n0 + wn * 64 + fn * 16 + l16;
            float bv = bias[col];
            f32x4 a = acc[fm][fn];
#pragma unroll
            for (int r = 0; r < 4; ++r)
                out[(size_t)(row0 + r) * N_DIM + col] = a[r] + bv;
        }
    }
}

extern "C" void kernel_launch(void* const* d_in, const int* in_sizes, int n_in,
                              void* d_out, int out_size, void* d_ws, size_t ws_size,
                              hipStream_t stream)
{
    const float* x      = (const float*)d_in[0];
    const int* qweight  = (const int*)d_in[1];
    const int* qzeros   = (const int*)d_in[2];
    const float* scales = (const float*)d_in[3];
    const float* bias   = (const float*)d_in[4];
    float* out          = (float*)d_out;

    const size_t WB = (size_t)N_DIM * K_DIM * 2;
    const size_t XB = (size_t)M_DIM * K_DIM * 2;

    if (ws_size >= WB + XB) {
        unsigned short* Wbf = (unsigned short*)d_ws;
        unsigned short* Xbf = (unsigned short*)((char*)d_ws + WB);
        dequant_w_kernel<<<dim3(22016), dim3(256), 0, stream>>>(qweight, qzeros, scales, Wbf);
        conv_x_kernel<<<dim3(8192), dim3(256), 0, stream>>>(x, Xbf);
        gemm256_kernel<<<dim3(688), dim3(512), 0, stream>>>(Xbf, Wbf, bias, out);
    } else {
        dim3 grid(N_DIM / 128, M_DIM / 128);
        gemm_fallback<<<grid, dim3(256), 0, stream>>>(x, qweight, qzeros, scales, bias, out);
    }
}